// Round 7
// baseline (417.689 us; speedup 1.0000x reference)
//
#include <hip/hip_runtime.h>

#define N_NODES 10000
#define NEDGE 160000
#define NB 80000  /* N_NODES*BATCH */
#define SCAN_CH 40 /* 256-wide chunks per array */

typedef unsigned int u32;
typedef unsigned short u16;
typedef __attribute__((ext_vector_type(8))) short short8;
typedef __attribute__((ext_vector_type(4))) float float4v;

__device__ __forceinline__ float bf2f(u16 h) { return __uint_as_float(((u32)h) << 16); }
__device__ __forceinline__ u16 f2bf(float f) {
    u32 u = __float_as_uint(f);
    return (u16)((u + 0x7fffu + ((u >> 16) & 1u)) >> 16);
}
__device__ __forceinline__ float lo16(u32 u) { return __uint_as_float(u << 16); }
__device__ __forceinline__ float hi16(u32 u) { return __uint_as_float(u & 0xffff0000u); }
__device__ __forceinline__ u32 pack2(float a, float b) {
    return (u32)f2bf(a) | (((u32)f2bf(b)) << 16);
}
__device__ __forceinline__ float fast_tanh(float v) {
    return 1.f - 2.f / (__expf(2.f * v) + 1.f);
}

// ---------------- prep: transpose + fused bpack12 + bpackP + zero cnt ----------------
__global__ __launch_bounds__(256) void prep_kernel(
    const float2* __restrict__ y, u32* __restrict__ X0,
    const float* __restrict__ W_lat, const float* __restrict__ W_units,
    u16* __restrict__ bpk12,
    const float* __restrict__ W_final, u16* __restrict__ bpkP,
    int* __restrict__ cnt) {
    int b = blockIdx.x, t = threadIdx.x;
    if (b < 10000) {
        int idx = b * 256 + t;  // NB*32 = 2.56M exactly
        int fh = idx & 31;
        int rb = idx >> 5;
        int bb = rb & 7;
        int n = rb >> 3;
        float2 v = y[((size_t)bb * N_NODES + n) * 32 + fh];
        X0[idx] = pack2(v.x, v.y);
    } else if (b < 10240) {
        // fused bpack: K=320 (k = m*64+f, wrow = f*5+m), NOUT=192 (0..63 lat, 64..191 units)
        int idx = (b - 10000) * 256 + t;  // < 61440
        int j = idx & 7;
        int lane = (idx >> 3) & 63;
        int rest = idx >> 9;
        int ct = rest % 12;
        int ks = rest / 12;
        int k = ks * 32 + (lane >> 4) * 8 + j;
        int col = ct * 16 + (lane & 15);
        int wrow = (k % 64) * 5 + (k / 64);
        float v = (col < 64) ? W_lat[wrow * 64 + col] : W_units[wrow * 128 + (col - 64)];
        bpk12[idx] = f2bf(v);
    } else if (b < 10400) {
        // bpackP: K=128, NOUT=320; slot0 = W[:,0]-W[:,2]-W[:,4], slot m>=1 = W[:,m]
        int idx = (b - 10240) * 256 + t;  // < 40960
        int j8 = idx & 7;
        int lane = (idx >> 3) & 63;
        int rest = idx >> 9;
        int ct = rest % 20;
        int ks = rest / 20;
        int k = ks * 32 + (lane >> 4) * 8 + j8;
        int col = ct * 16 + (lane & 15);
        int slot = col >> 6, j = col & 63;
        float v;
        if (slot == 0)
            v = W_final[(k * 5 + 0) * 64 + j] - W_final[(k * 5 + 2) * 64 + j] -
                W_final[(k * 5 + 4) * 64 + j];
        else
            v = W_final[(k * 5 + slot) * 64 + j];
        bpkP[idx] = f2bf(v);
    } else {
        int idx = (b - 10400) * 256 + t;
        if (idx < 2 * N_NODES) cnt[idx] = 0;
    }
}

// ---------------- CSR build ----------------
__global__ void count_kernel(const int* __restrict__ rows, const int* __restrict__ cols,
                             int* __restrict__ cnt1, int* __restrict__ cnt2) {
    int e = blockIdx.x * 256 + threadIdx.x;
    if (e < NEDGE) {
        atomicAdd(&cnt1[cols[e]], 1);  // support1: dst = cols
        atomicAdd(&cnt2[rows[e]], 1);  // support2: dst = rows
    }
}

__global__ void blocksum_kernel(const int* __restrict__ cnt, int* __restrict__ bsums) {
    __shared__ int red[4];
    int arr = blockIdx.x / SCAN_CH;
    int c = blockIdx.x % SCAN_CH;
    int idx = c * 256 + threadIdx.x;
    int v = (idx < N_NODES) ? cnt[arr * N_NODES + idx] : 0;
#pragma unroll
    for (int off = 32; off; off >>= 1) v += __shfl_down(v, off, 64);
    int wv = threadIdx.x >> 6, ln = threadIdx.x & 63;
    if (ln == 0) red[wv] = v;
    __syncthreads();
    if (threadIdx.x == 0) bsums[blockIdx.x] = red[0] + red[1] + red[2] + red[3];
}

__global__ void scanmid_kernel(int* __restrict__ bsums, int* __restrict__ rowptr1,
                               int* __restrict__ rowptr2) {
    __shared__ int lds[128];
    int t = threadIdx.x;
    int seg = t >> 6, pos = t & 63;
    int v = (pos < SCAN_CH) ? bsums[seg * SCAN_CH + pos] : 0;
    lds[t] = v;
    __syncthreads();
    for (int off = 1; off < 64; off <<= 1) {
        int add = (pos >= off) ? lds[t - off] : 0;
        __syncthreads();
        lds[t] += add;
        __syncthreads();
    }
    if (pos < SCAN_CH) bsums[seg * SCAN_CH + pos] = pos ? lds[t - 1] : 0;
    if (t == 0) { rowptr1[N_NODES] = NEDGE; rowptr2[N_NODES] = NEDGE; }
}

__global__ void scanapply_kernel(int* __restrict__ cnt, const int* __restrict__ bsums,
                                 int* __restrict__ rowptr1, int* __restrict__ rowptr2) {
    __shared__ int lds[256];
    int arr = blockIdx.x / SCAN_CH;
    int c = blockIdx.x % SCAN_CH;
    int idx = c * 256 + threadIdx.x;
    bool ok = idx < N_NODES;
    int v = ok ? cnt[arr * N_NODES + idx] : 0;
    int t = threadIdx.x;
    lds[t] = v;
    __syncthreads();
    for (int off = 1; off < 256; off <<= 1) {
        int add = (t >= off) ? lds[t - off] : 0;
        __syncthreads();
        lds[t] += add;
        __syncthreads();
    }
    int excl = lds[t] - v + bsums[blockIdx.x];
    if (ok) {
        int* rp = arr ? rowptr2 : rowptr1;
        rp[idx] = excl;
        cnt[arr * N_NODES + idx] = excl;  // cursor
    }
}

__global__ void scatter_kernel(const int* __restrict__ rows, const int* __restrict__ cols,
                               const float* __restrict__ w1, const float* __restrict__ w2,
                               int* __restrict__ cur1, int* __restrict__ cur2,
                               int2* __restrict__ edges1, int2* __restrict__ edges2) {
    int e = blockIdx.x * 256 + threadIdx.x;
    if (e < NEDGE) {
        int r = rows[e], c = cols[e];
        int p1 = atomicAdd(&cur1[c], 1);
        edges1[p1] = make_int2(r, __float_as_int(w1[e]));
        int p2 = atomicAdd(&cur2[r], 1);
        edges2[p2] = make_int2(c, __float_as_int(w2[e]));
    }
}

// ---------------- col-sharded SpMM: wave = 2 nodes x 32 lanes, col-eighth per block ---
// Each lane accumulates one u32 (2 bf16) of its node's 256-u32 row, at column offset
// coff = (blockIdx%8)*32. XCD-pinned via blockIdx%8 so each XCD's L2 holds one
// col-slice (2.5 MB) of the gathered arrays.
__device__ __forceinline__ void gather_slice(const u32* __restrict__ Xin,
                                             const int* __restrict__ rp,
                                             const int2* __restrict__ eg,
                                             int n, int half, int hl, int coff,
                                             float& a0, float& a1) {
    int e0 = rp[n], e1 = rp[n + 1];
    int len = e1 - e0;
    int olen = __shfl(len, (threadIdx.x & 63) ^ 32, 64);
    int rounds = (max(len, olen) + 31) >> 5;
    for (int r = 0; r < rounds; r++) {
        int2 me = make_int2(0, 0);
        int ei = r * 32 + hl;
        if (ei < len) me = eg[e0 + ei];
        int sb = half << 5;
#pragma unroll
        for (int j = 0; j < 32; j += 4) {
            int s0 = __shfl(me.x, sb + j, 64);
            int s1 = __shfl(me.x, sb + j + 1, 64);
            int s2 = __shfl(me.x, sb + j + 2, 64);
            int s3 = __shfl(me.x, sb + j + 3, 64);
            float w0 = __int_as_float(__shfl(me.y, sb + j, 64));
            float w1 = __int_as_float(__shfl(me.y, sb + j + 1, 64));
            float w2 = __int_as_float(__shfl(me.y, sb + j + 2, 64));
            float w3 = __int_as_float(__shfl(me.y, sb + j + 3, 64));
            u32 u0 = Xin[(size_t)s0 * 256 + coff + hl];
            u32 u1 = Xin[(size_t)s1 * 256 + coff + hl];
            u32 u2 = Xin[(size_t)s2 * 256 + coff + hl];
            u32 u3 = Xin[(size_t)s3 * 256 + coff + hl];
            a0 += w0 * lo16(u0); a1 += w0 * hi16(u0);
            a0 += w1 * lo16(u1); a1 += w1 * hi16(u1);
            a0 += w2 * lo16(u2); a1 += w2 * hi16(u2);
            a0 += w3 * lo16(u3); a1 += w3 * hi16(u3);
        }
    }
}

// dual-list axpby: virtual group g<1250 -> list1/A ptrs, else list2/B ptrs
__global__ __launch_bounds__(256) void spmm8_kernel(
    const u32* __restrict__ XinA, const u32* __restrict__ XprevA, u32* __restrict__ XoutA,
    const u32* __restrict__ XinB, const u32* __restrict__ XprevB, u32* __restrict__ XoutB,
    const int* __restrict__ rowptr1, const int2* __restrict__ edges1,
    const int* __restrict__ rowptr2, const int2* __restrict__ edges2,
    float alpha, float beta) {
    int lane = threadIdx.x & 63;
    int wave = threadIdx.x >> 6;
    int half = lane >> 5, hl = lane & 31;
    int col = blockIdx.x & 7;
    int g = blockIdx.x >> 3;  // 0..2499
    int coff = col * 32;
    bool hB = g >= 1250;
    int n = (hB ? g - 1250 : g) * 8 + wave * 2 + half;
    const u32* Xin = hB ? XinB : XinA;
    const u32* Xprev = hB ? XprevB : XprevA;
    u32* Xout = hB ? XoutB : XoutA;
    const int* rp = hB ? rowptr2 : rowptr1;
    const int2* eg = hB ? edges2 : edges1;

    float a0 = 0.f, a1 = 0.f;
    gather_slice(Xin, rp, eg, n, half, hl, coff, a0, a1);

    size_t o = (size_t)n * 256 + coff + hl;
    float r0 = alpha * a0, r1 = alpha * a1;
    if (beta != 0.f) {
        u32 p = Xprev[o];
        r0 += beta * lo16(p);
        r1 += beta * hi16(p);
    }
    Xout[o] = pack2(r0, r1);
}

// final: out = -theta * tanh(Q + S1@T1 + S2@T2), fp32 (B,N,64) layout
__global__ __launch_bounds__(256) void spmm8_final_kernel(
    const u32* __restrict__ T1, const u32* __restrict__ T2,
    const u32* __restrict__ Q, const u32* __restrict__ theta,
    const int* __restrict__ rowptr1, const int2* __restrict__ edges1,
    const int* __restrict__ rowptr2, const int2* __restrict__ edges2,
    float* __restrict__ outF) {
    int lane = threadIdx.x & 63;
    int wave = threadIdx.x >> 6;
    int half = lane >> 5, hl = lane & 31;
    int col = blockIdx.x & 7;
    int g = blockIdx.x >> 3;  // 0..1249
    int coff = col * 32;
    int n = g * 8 + wave * 2 + half;

    float a0 = 0.f, a1 = 0.f;
    gather_slice(T1, rowptr1, edges1, n, half, hl, coff, a0, a1);
    gather_slice(T2, rowptr2, edges2, n, half, hl, coff, a0, a1);

    size_t o = (size_t)n * 256 + coff + hl;
    u32 q = Q[o];
    u32 th = theta[o];
    float v0 = fast_tanh(lo16(q) + a0);
    float v1 = fast_tanh(hi16(q) + a1);
    int idx = coff + hl;          // 0..255 within row
    int b = idx >> 5;             // batch
    int f0 = (idx & 31) * 2;      // feature pair
    *(float2*)(outF + (size_t)b * (N_NODES * 64) + (size_t)n * 64 + f0) =
        make_float2(-lo16(th) * v0, -hi16(th) * v1);
}

// ---------------- MFMA GEMM: 64 rows/block (4 waves x 16 rows), optional col-split ---
struct Slabs { const u16* p[5]; };

// MODE 0: plain (+bias1 on cols<64) -> 64-wide slabs at O1
// MODE 1: fused: col<64 sigmoid(+bias1)->O1 (64-wide); col>=64 tanh(+bias2)->O2 (128-wide)
template <int FIN, int NM, int NOUT, int NSPLIT, int MODE>
__global__ __launch_bounds__(256) void gemm_kernel(
    Slabs A, const u16* __restrict__ Bp, const float* __restrict__ bias1,
    const float* __restrict__ bias2, u16* __restrict__ O1, u16* __restrict__ O2) {
    constexpr int K = NM * FIN;
    constexpr int KS = K / 32;
    constexpr int CTT = NOUT / 16;
    constexpr int CT = CTT / NSPLIT;
    int lane = threadIdx.x & 63;
    int wave = threadIdx.x >> 6;
    int rowBase = (blockIdx.x / NSPLIT) * 64 + wave * 16;
    int ctBase = (blockIdx.x % NSPLIT) * CT;
    int mrow = lane & 15;
    int kq = lane >> 4;

    float4v acc[CT];
#pragma unroll
    for (int c = 0; c < CT; c++) acc[c] = (float4v){0.f, 0.f, 0.f, 0.f};

#pragma unroll
    for (int ks = 0; ks < KS; ks++) {
        int k = ks * 32 + kq * 8;
        int m = k / FIN;  // uniform within ks
        int koff = k % FIN;
        short8 a = *(const short8*)(A.p[m] + (size_t)(rowBase + mrow) * FIN + koff);
        short8 b[CT];
#pragma unroll
        for (int ct = 0; ct < CT; ct++)
            b[ct] = *(const short8*)(Bp + ((size_t)(ks * CTT + ctBase + ct) * 64 + lane) * 8);
#pragma unroll
        for (int ct = 0; ct < CT; ct++)
            acc[ct] = __builtin_amdgcn_mfma_f32_16x16x32_bf16(a, b[ct], acc[ct], 0, 0, 0);
    }

    int rowq = rowBase + kq * 4;
#pragma unroll
    for (int ct = 0; ct < CT; ct++) {
        int col = (ctBase + ct) * 16 + mrow;
        float bsv;
        if (MODE == 0) bsv = (col < 64) ? bias1[col] : 0.f;
        else bsv = (col < 64) ? bias1[col] : bias2[col - 64];
#pragma unroll
        for (int i = 0; i < 4; i++) {
            float v = acc[ct][i] + bsv;
            int r = rowq + i;
            if (MODE == 0) {
                O1[(size_t)(col >> 6) * ((size_t)NB * 64) + (size_t)r * 64 + (col & 63)] = f2bf(v);
            } else {
                if (col < 64) {
                    v = 1.f / (1.f + __expf(-v));
                    O1[(size_t)r * 64 + col] = f2bf(v);
                } else {
                    O2[(size_t)r * 128 + (col - 64)] = f2bf(fast_tanh(v));
                }
            }
        }
    }
}

// ---------------- launch ----------------
extern "C" void kernel_launch(void* const* d_in, const int* in_sizes, int n_in,
                              void* d_out, int out_size, void* d_ws, size_t ws_size,
                              hipStream_t stream) {
    const float* y     = (const float*)d_in[0];
    const float* W_lat = (const float*)d_in[1];
    const float* b_lat = (const float*)d_in[2];
    const float* W_units = (const float*)d_in[3];
    const float* b_units = (const float*)d_in[4];
    const float* W_final = (const float*)d_in[5];
    const float* sup1w = (const float*)d_in[6];
    const float* sup2w = (const float*)d_in[7];
    const int* rows    = (const int*)d_in[8];
    const int* cols    = (const int*)d_in[9];
    float* out = (float*)d_out;

    char* ws = (char*)d_ws;
    size_t off = 0;
    auto alloc = [&](size_t bytes) -> void* {
        void* p = ws + off;
        off += (bytes + 511) & ~(size_t)511;
        return p;
    };
    int* rowptr1 = (int*)alloc((N_NODES + 1) * 4);
    int* rowptr2 = (int*)alloc((N_NODES + 1) * 4);
    int* cnt = (int*)alloc((size_t)2 * N_NODES * 4);
    int* cnt1 = cnt;
    int* cnt2 = cnt + N_NODES;
    int* bsums = (int*)alloc(2 * SCAN_CH * 4);
    int2* edges1 = (int2*)alloc((size_t)NEDGE * 8);
    int2* edges2 = (int2*)alloc((size_t)NEDGE * 8);
    u16* bpk12 = (u16*)alloc((size_t)61440 * 2);
    u16* bpkP = (u16*)alloc((size_t)40960 * 2);
    u16* theta = (u16*)alloc((size_t)NB * 64 * 2);
    u16* S = (u16*)alloc((size_t)5 * NB * 64 * 2);  // X-series; later overlaid by Q/P slabs
    u16* H0 = (u16*)alloc((size_t)NB * 128 * 2);
    u16* T1 = (u16*)alloc((size_t)NB * 64 * 2);
    u16* T2 = (u16*)alloc((size_t)NB * 64 * 2);
    u16* P = S;  // Q/P slabs overlay S (S dead after gemm12)

    const size_t SLAB = (size_t)NB * 64;

    prep_kernel<<<10479, 256, 0, stream>>>((const float2*)y, (u32*)S, W_lat, W_units,
                                           bpk12, W_final, bpkP, cnt);
    count_kernel<<<(NEDGE + 255) / 256, 256, 0, stream>>>(rows, cols, cnt1, cnt2);
    blocksum_kernel<<<2 * SCAN_CH, 256, 0, stream>>>(cnt, bsums);
    scanmid_kernel<<<1, 128, 0, stream>>>(bsums, rowptr1, rowptr2);
    scanapply_kernel<<<2 * SCAN_CH, 256, 0, stream>>>(cnt, bsums, rowptr1, rowptr2);
    scatter_kernel<<<(NEDGE + 255) / 256, 256, 0, stream>>>(rows, cols, sup1w, sup2w,
                                                            cnt1, cnt2, edges1, edges2);

    // x-side diffusion: X1 = S1@X0, X3 = S2@X0 ; X2 = 2*S1@X1 - X0, X4 = 2*S2@X3 - X0
    const u32* S0 = (const u32*)S;
    u32* X1 = (u32*)(S + 1 * SLAB);
    u32* X2 = (u32*)(S + 2 * SLAB);
    u32* X3 = (u32*)(S + 3 * SLAB);
    u32* X4 = (u32*)(S + 4 * SLAB);
    spmm8_kernel<<<20000, 256, 0, stream>>>(S0, nullptr, X1, S0, nullptr, X3,
                                            rowptr1, edges1, rowptr2, edges2, 1.f, 0.f);
    spmm8_kernel<<<20000, 256, 0, stream>>>(X1, S0, X2, X3, S0, X4,
                                            rowptr1, edges1, rowptr2, edges2, 2.f, -1.f);

    Slabs SX;
    for (int m = 0; m < 5; m++) SX.p[m] = S + (size_t)m * SLAB;
    // fused: theta = sigmoid(X@W_lat + b_lat), H0 = tanh(X@W_units + b_units)
    gemm_kernel<64, 5, 192, 1, 1><<<1250, 256, 0, stream>>>(SX, bpk12, b_lat, b_units, theta, H0);

    // P-GEMM: [Q|P1|P2|P3|P4] = H0 @ bpkP (Q = P0-P2-P4 + b_lat), overlays S
    Slabs SH;
    SH.p[0] = H0;
    gemm_kernel<128, 1, 320, 2, 0><<<2500, 256, 0, stream>>>(SH, bpkP, b_lat, nullptr, P, nullptr);

    const u32* Q  = (const u32*)(P + 0 * SLAB);
    const u32* P1 = (const u32*)(P + 1 * SLAB);
    const u32* P2 = (const u32*)(P + 2 * SLAB);
    const u32* P3 = (const u32*)(P + 3 * SLAB);
    const u32* P4 = (const u32*)(P + 4 * SLAB);
    // T1 = P1 + 2*S1@P2 ; T2 = P3 + 2*S2@P4
    spmm8_kernel<<<20000, 256, 0, stream>>>(P2, (const u32*)P1, (u32*)T1,
                                            P4, (const u32*)P3, (u32*)T2,
                                            rowptr1, edges1, rowptr2, edges2, 2.f, 1.f);
    // out = -theta * tanh(Q + S1@T1 + S2@T2)
    spmm8_final_kernel<<<10000, 256, 0, stream>>>((const u32*)T1, (const u32*)T2, Q,
                                                  (const u32*)theta,
                                                  rowptr1, edges1, rowptr2, edges2, out);
}